// Round 1
// baseline (220.068 us; speedup 1.0000x reference)
//
#include <hip/hip_runtime.h>
#include <math.h>

#define N_S 8192
#define N_T 4096
#define DIN 128
#define NF  64

__device__ __forceinline__ float lrelu(float x){ return x > 0.f ? x : 0.1f*x; }

// ---------------- K1: projections Whs=hs@Ws, Wht=ht@Wt, Whst=Whs@a_s, Whtt=Wht@a_t
__global__ __launch_bounds__(256) void proj_kernel(
    const float* __restrict__ hs, const float* __restrict__ ht,
    const float* __restrict__ Ws, const float* __restrict__ Wt,
    const float* __restrict__ a1,
    float* __restrict__ Whs, float* __restrict__ Wht,
    float* __restrict__ Whst, float* __restrict__ Whtt)
{
  __shared__ float Wl[DIN*NF];
  __shared__ float hrow[4*DIN];
  int b = blockIdx.x;
  bool is_s = b < (N_S/4);
  const float* h; const float* W; const float* av; float* Wout; float* dout;
  int r0;
  if (is_s) { r0 = b*4;           h = hs; W = Ws; av = a1 + 64; Wout = Whs; dout = Whst; }
  else      { r0 = (b - N_S/4)*4; h = ht; W = Wt; av = a1;      Wout = Wht; dout = Whtt; }
  int t = threadIdx.x;
  for (int i = t; i < DIN*NF; i += 256) Wl[i] = W[i];
  for (int i = t; i < 4*DIN;  i += 256) hrow[i] = h[(size_t)r0*DIN + i];
  __syncthreads();
  int f = t & 63, sr = t >> 6;
  float acc = 0.f;
  #pragma unroll 8
  for (int k = 0; k < DIN; ++k) acc += hrow[sr*DIN + k] * Wl[k*NF + f];
  int r = r0 + sr;
  Wout[(size_t)r*NF + f] = acc;
  float p = acc * av[f];
  #pragma unroll
  for (int o = 32; o > 0; o >>= 1) p += __shfl_xor(p, o, 64);
  if (f == 0) dout[r] = p;
}

// ---------------- K1b: global maxes of Whst (->mx[0]) and Whtt (->mx[1])
__global__ __launch_bounds__(256) void max_kernel(
    const float* __restrict__ Whst, const float* __restrict__ Whtt, float* __restrict__ mx)
{
  const float* src = blockIdx.x == 0 ? Whst : Whtt;
  int n = blockIdx.x == 0 ? N_S : N_T;
  int t = threadIdx.x;
  float m = -1e30f;
  for (int i = t; i < n; i += 256) m = fmaxf(m, src[i]);
  __shared__ float red[4];
  #pragma unroll
  for (int o = 32; o > 0; o >>= 1) m = fmaxf(m, __shfl_xor(m, o, 64));
  if ((t & 63) == 0) red[t >> 6] = m;
  __syncthreads();
  if (t == 0) mx[blockIdx.x] = fmaxf(fmaxf(red[0], red[1]), fmaxf(red[2], red[3]));
}

// ---------------- K2/K3: masked-softmax weighted aggregation (unnormalized) + row sums
// DIR=0 (st): out rows u = i in [0,4096), contraction k = j in [0,8192)
//             w = mask(u,k) * exp(lrelu(Whtt[u]+Whst[k]) - lrelu(Whtt[u]+maxWhst)); X = Whs
// DIR=1 (ts): out rows u = j in [0,8192), contraction k = i in [0,4096)
//             w = mask(k,u) * exp(lrelu(Whst[u]+Whtt[k]) - lrelu(Whst[u]+maxWhtt)); X = Wht
template<int DIR>
__global__ __launch_bounds__(256) void agg_kernel(
    const int*   __restrict__ A,
    const float* __restrict__ baseU,
    const float* __restrict__ valK,
    const float* __restrict__ X,
    const float* __restrict__ mx,
    float* __restrict__ accG,
    float* __restrict__ sumG,
    int kchunk)
{
  __shared__ __align__(16) float wT[64*68];   // DIR0: [u][k]  DIR1: [k][u]  (stride 68 f32)
  __shared__ __align__(16) float xT[64*68];   // [k][f]
  __shared__ float rowsum[64];
  int t = threadIdx.x;
  int u0 = blockIdx.x * 64;
  int kc0 = blockIdx.y * kchunk;
  float mother = mx[DIR];
  int lane16 = t & 15;   // quartet column index
  int grp16  = t >> 4;   // row-within-pass (0..15)
  float4 baseC4, MC4;
  if (DIR == 1) {
    baseC4 = *(const float4*)&baseU[u0 + 4*lane16];
    MC4.x = lrelu(baseC4.x + mother); MC4.y = lrelu(baseC4.y + mother);
    MC4.z = lrelu(baseC4.z + mother); MC4.w = lrelu(baseC4.w + mother);
  }
  if (t < 64) rowsum[t] = 0.f;
  float acc[4][4];
  #pragma unroll
  for (int q = 0; q < 4; ++q) { acc[q][0]=0.f; acc[q][1]=0.f; acc[q][2]=0.f; acc[q][3]=0.f; }
  int tu = t >> 4, tf = t & 15;

  for (int k0 = kc0; k0 < kc0 + kchunk; k0 += 64) {
    // ---- build w tile ----
    if (DIR == 0) {
      float4 vk4 = *(const float4*)&valK[k0 + 4*lane16];
      #pragma unroll
      for (int s = 0; s < 4; ++s) {
        int uu = s*16 + grp16;
        const int4 m4 = *(const int4*)&A[(size_t)(u0+uu)*N_S + k0 + 4*lane16];
        float bu = baseU[u0+uu];
        float Mu = lrelu(bu + mother);
        float4 w;
        w.x = m4.x > 0 ? __expf(lrelu(bu + vk4.x) - Mu) : 0.f;
        w.y = m4.y > 0 ? __expf(lrelu(bu + vk4.y) - Mu) : 0.f;
        w.z = m4.z > 0 ? __expf(lrelu(bu + vk4.z) - Mu) : 0.f;
        w.w = m4.w > 0 ? __expf(lrelu(bu + vk4.w) - Mu) : 0.f;
        *(float4*)&wT[uu*68 + 4*lane16] = w;
      }
    } else {
      #pragma unroll
      for (int s = 0; s < 4; ++s) {
        int kk = s*16 + grp16;
        const int4 m4 = *(const int4*)&A[(size_t)(k0+kk)*N_S + u0 + 4*lane16];
        float vk = valK[k0+kk];
        float4 w;
        w.x = m4.x > 0 ? __expf(lrelu(baseC4.x + vk) - MC4.x) : 0.f;
        w.y = m4.y > 0 ? __expf(lrelu(baseC4.y + vk) - MC4.y) : 0.f;
        w.z = m4.z > 0 ? __expf(lrelu(baseC4.z + vk) - MC4.z) : 0.f;
        w.w = m4.w > 0 ? __expf(lrelu(baseC4.w + vk) - MC4.w) : 0.f;
        *(float4*)&wT[kk*68 + 4*lane16] = w;
      }
    }
    // ---- x tile [k][f] ----
    #pragma unroll
    for (int s = 0; s < 4; ++s) {
      int kk = s*16 + grp16;
      float4 xv = *(const float4*)&X[(size_t)(k0+kk)*NF + 4*lane16];
      *(float4*)&xT[kk*68 + 4*lane16] = xv;
    }
    __syncthreads();
    // ---- accumulate row sums of w (denominators) ----
    {
      int uu = t >> 2, q = t & 3;
      float p = 0.f;
      #pragma unroll
      for (int cc = 0; cc < 16; ++cc)
        p += (DIR == 0) ? wT[uu*68 + q*16 + cc] : wT[(q*16+cc)*68 + uu];
      p += __shfl_xor(p, 1, 64);
      p += __shfl_xor(p, 2, 64);
      if (q == 0) rowsum[uu] += p;
    }
    // ---- 64x64x64 f32 tile MAC ----
    if (DIR == 0) {
      #pragma unroll 4
      for (int k = 0; k < 64; k += 4) {
        float4 wv[4];
        #pragma unroll
        for (int q = 0; q < 4; ++q) wv[q] = *(const float4*)&wT[(tu*4+q)*68 + k];
        #pragma unroll
        for (int kk = 0; kk < 4; ++kk) {
          float4 xv = *(const float4*)&xT[(k+kk)*68 + tf*4];
          #pragma unroll
          for (int q = 0; q < 4; ++q) {
            float w = kk==0 ? wv[q].x : kk==1 ? wv[q].y : kk==2 ? wv[q].z : wv[q].w;
            acc[q][0] += w*xv.x; acc[q][1] += w*xv.y; acc[q][2] += w*xv.z; acc[q][3] += w*xv.w;
          }
        }
      }
    } else {
      #pragma unroll 8
      for (int k = 0; k < 64; ++k) {
        float4 wv = *(const float4*)&wT[k*68 + tu*4];
        float4 xv = *(const float4*)&xT[k*68 + tf*4];
        acc[0][0] += wv.x*xv.x; acc[0][1] += wv.x*xv.y; acc[0][2] += wv.x*xv.z; acc[0][3] += wv.x*xv.w;
        acc[1][0] += wv.y*xv.x; acc[1][1] += wv.y*xv.y; acc[1][2] += wv.y*xv.z; acc[1][3] += wv.y*xv.w;
        acc[2][0] += wv.z*xv.x; acc[2][1] += wv.z*xv.y; acc[2][2] += wv.z*xv.z; acc[2][3] += wv.z*xv.w;
        acc[3][0] += wv.w*xv.x; acc[3][1] += wv.w*xv.y; acc[3][2] += wv.w*xv.z; acc[3][3] += wv.w*xv.w;
      }
    }
    __syncthreads();
  }
  #pragma unroll
  for (int q = 0; q < 4; ++q) {
    int u = u0 + tu*4 + q;
    #pragma unroll
    for (int e = 0; e < 4; ++e)
      atomicAdd(&accG[(size_t)u*NF + tf*4 + e], acc[q][e]);
  }
  if (t < 64) atomicAdd(&sumG[u0 + t], rowsum[t]);
}

// ---------------- K4: normalize + bias + elu, write both outputs
__global__ __launch_bounds__(256) void finalize_kernel(
    const float* __restrict__ accST, const float* __restrict__ sumST,
    const float* __restrict__ accTS, const float* __restrict__ sumTS,
    const float* __restrict__ bias_s, const float* __restrict__ bias_t,
    float* __restrict__ out)
{
  int idx = blockIdx.x*256 + threadIdx.x;
  const int n0 = N_T*NF;
  float v;
  if (idx < n0) {
    int u = idx >> 6, f = idx & 63;
    float s = sumST[u];
    float r = s > 0.f ? accST[idx]/s : 0.f;
    v = r + bias_s[f];
  } else {
    int i2 = idx - n0;
    int u = i2 >> 6, f = i2 & 63;
    float s = sumTS[u];
    float r = s > 0.f ? accTS[i2]/s : 0.f;
    v = r + bias_t[f];
  }
  out[idx] = v > 0.f ? v : expm1f(v);
}

extern "C" void kernel_launch(void* const* d_in, const int* in_sizes, int n_in,
                              void* d_out, int out_size, void* d_ws, size_t ws_size,
                              hipStream_t stream)
{
  const float* hs     = (const float*)d_in[0];
  const float* ht     = (const float*)d_in[1];
  const int*   A      = (const int*)  d_in[2];
  const float* Ws     = (const float*)d_in[3];
  const float* Wt     = (const float*)d_in[4];
  const float* a1     = (const float*)d_in[5];
  const float* bias_s = (const float*)d_in[6];
  const float* bias_t = (const float*)d_in[7];
  float* out = (float*)d_out;

  float* ws    = (float*)d_ws;
  float* Whs   = ws;                  // 8192*64
  float* Wht   = Whs  + (size_t)N_S*NF; // 4096*64
  float* Whst  = Wht  + (size_t)N_T*NF; // 8192
  float* Whtt  = Whst + N_S;            // 4096
  float* mx    = Whtt + N_T;            // 16 (padded)
  float* accST = mx   + 16;             // 4096*64
  float* sumST = accST + (size_t)N_T*NF;// 4096
  float* accTS = sumST + N_T;           // 8192*64
  float* sumTS = accTS + (size_t)N_S*NF;// 8192

  // zero the accumulators (contiguous region accST..sumTS)
  hipMemsetAsync(accST, 0,
                 ((size_t)N_T*NF + N_T + (size_t)N_S*NF + N_S) * sizeof(float), stream);

  proj_kernel<<<(N_S + N_T)/4, 256, 0, stream>>>(hs, ht, Ws, Wt, a1, Whs, Wht, Whst, Whtt);
  max_kernel<<<2, 256, 0, stream>>>(Whst, Whtt, mx);
  agg_kernel<0><<<dim3(N_T/64, 8), 256, 0, stream>>>(A, Whtt, Whst, Whs, mx, accST, sumST, N_S/8);
  agg_kernel<1><<<dim3(N_S/64, 4), 256, 0, stream>>>(A, Whst, Whtt, Wht, mx, accTS, sumTS, N_T/4);
  finalize_kernel<<<(N_T*NF + N_S*NF)/256, 256, 0, stream>>>(accST, sumST, accTS, sumTS,
                                                             bias_s, bias_t, out);
}

// Round 2
// 143.558 us; speedup vs baseline: 1.5330x; 1.5330x over previous
//
#include <hip/hip_runtime.h>
#include <math.h>

#define N_S 8192
#define N_T 4096
#define DIN 128
#define NF  64

typedef __attribute__((ext_vector_type(8))) short short8;
typedef __attribute__((ext_vector_type(4))) float f32x4;

__device__ __forceinline__ float lrelu(float x){ return x > 0.f ? x : 0.1f*x; }

// round-to-nearest-even f32 -> bf16 bits
__device__ __forceinline__ unsigned short f2bf(float x){
  unsigned u = __float_as_uint(x);
  unsigned r = (u + 0x7fffu + ((u >> 16) & 1u)) >> 16;
  return (unsigned short)r;
}
__device__ __forceinline__ float bf2f(unsigned short s){
  return __uint_as_float(((unsigned)s) << 16);
}

// ---------------- K1: projections. Writes bf16 TRANSPOSED XT[f][row] for the MFMA B-operand,
// plus f32 attention vectors Whst = Whs@a_s, Whtt = Wht@a_t.
__global__ __launch_bounds__(256) void proj_kernel(
    const float* __restrict__ hs, const float* __restrict__ ht,
    const float* __restrict__ Ws, const float* __restrict__ Wt,
    const float* __restrict__ a1,
    unsigned short* __restrict__ XsT, unsigned short* __restrict__ XtT,
    float* __restrict__ Whst, float* __restrict__ Whtt)
{
  __shared__ float Wl[DIN*NF];
  __shared__ float hrow[4*DIN];
  int b = blockIdx.x;
  bool is_s = b < (N_S/4);
  const float* h; const float* W; const float* av;
  unsigned short* XT; float* dout; int r0, NR;
  if (is_s) { r0 = b*4;           h = hs; W = Ws; av = a1 + 64; XT = XsT; dout = Whst; NR = N_S; }
  else      { r0 = (b - N_S/4)*4; h = ht; W = Wt; av = a1;      XT = XtT; dout = Whtt; NR = N_T; }
  int t = threadIdx.x;
  for (int i = t; i < DIN*NF; i += 256) Wl[i] = W[i];
  for (int i = t; i < 4*DIN;  i += 256) hrow[i] = h[(size_t)r0*DIN + i];
  __syncthreads();
  int f = t & 63, sr = t >> 6;
  float acc = 0.f;
  #pragma unroll 8
  for (int k = 0; k < DIN; ++k) acc += hrow[sr*DIN + k] * Wl[k*NF + f];
  int r = r0 + sr;
  XT[(size_t)f*NR + r] = f2bf(acc);
  float p = acc * av[f];
  #pragma unroll
  for (int o = 32; o > 0; o >>= 1) p += __shfl_xor(p, o, 64);
  if (f == 0) dout[r] = p;
}

// ---------------- K1b: global maxes of Whst (->mx[0]) and Whtt (->mx[1])
__global__ __launch_bounds__(256) void max_kernel(
    const float* __restrict__ Whst, const float* __restrict__ Whtt, float* __restrict__ mx)
{
  const float* src = blockIdx.x == 0 ? Whst : Whtt;
  int n = blockIdx.x == 0 ? N_S : N_T;
  int t = threadIdx.x;
  float m = -1e30f;
  for (int i = t; i < n; i += 256) m = fmaxf(m, src[i]);
  __shared__ float red[4];
  #pragma unroll
  for (int o = 32; o > 0; o >>= 1) m = fmaxf(m, __shfl_xor(m, o, 64));
  if ((t & 63) == 0) red[t >> 6] = m;
  __syncthreads();
  if (t == 0) mx[blockIdx.x] = fmaxf(fmaxf(red[0], red[1]), fmaxf(red[2], red[3]));
}

// ---------------- K2/K3: masked-softmax weighted aggregation via MFMA bf16.
// DIR=0 (st): rows u = i in [0,4096), k = j in [0,8192); mask A[u][k]; X = Whs^T (XsT)
// DIR=1 (ts): rows u = j in [0,8192), k = i in [0,4096); mask A[k][u]; X = Wht^T (XtT)
// w = mask * exp(lrelu(baseU[u]+valK[k]) - lrelu(baseU[u]+mother))   (arg <= 0 always)
// Per wave: 16 output rows x 64 features; A-frags (w) built in registers, B-frags
// (x) loaded from global bf16 transposed XT[f][k] (L2-resident). No LDS, no barriers.
template<int DIR>
__global__ __launch_bounds__(256, 4) void agg_mfma(
    const int*   __restrict__ A,
    const float* __restrict__ baseU,
    const float* __restrict__ valK,
    const unsigned short* __restrict__ XT,
    const float* __restrict__ mx,
    float* __restrict__ accG,
    float* __restrict__ sumG,
    int kchunk)
{
  constexpr int NK = (DIR == 0) ? N_S : N_T;   // contraction length / XT row stride
  int t = threadIdx.x;
  int wave = t >> 6, l = t & 63;
  int row16 = l & 15, grp = l >> 4;            // frag k-offset = grp*8
  int u = blockIdx.x*64 + wave*16 + row16;
  float mother = mx[DIR];
  float bu = baseU[u];
  float Mu = lrelu(bu + mother);
  f32x4 acc[4];
  #pragma unroll
  for (int q = 0; q < 4; ++q) { acc[q][0]=0.f; acc[q][1]=0.f; acc[q][2]=0.f; acc[q][3]=0.f; }
  float sw = 0.f;
  int kc0 = blockIdx.y * kchunk;

  for (int k0 = kc0; k0 < kc0 + kchunk; k0 += 64) {
    short8 af0, af1;
    #pragma unroll
    for (int h = 0; h < 2; ++h) {
      int kb = k0 + 32*h + grp*8;
      float4 v0 = *(const float4*)&valK[kb];
      float4 v1 = *(const float4*)&valK[kb + 4];
      float vv[8] = {v0.x, v0.y, v0.z, v0.w, v1.x, v1.y, v1.z, v1.w};
      int mm[8];
      if (DIR == 0) {
        int4 m0 = *(const int4*)&A[(size_t)u*N_S + kb];
        int4 m1 = *(const int4*)&A[(size_t)u*N_S + kb + 4];
        mm[0]=m0.x; mm[1]=m0.y; mm[2]=m0.z; mm[3]=m0.w;
        mm[4]=m1.x; mm[5]=m1.y; mm[6]=m1.z; mm[7]=m1.w;
      } else {
        #pragma unroll
        for (int j = 0; j < 8; ++j) mm[j] = A[(size_t)(kb + j)*N_S + u];
      }
      short8 af;
      #pragma unroll
      for (int j = 0; j < 8; ++j) {
        float w = mm[j] > 0 ? __expf(lrelu(bu + vv[j]) - Mu) : 0.f;
        unsigned short bits = f2bf(w);
        sw += bf2f(bits);               // denominator matches bf16-rounded numerator
        af[j] = (short)bits;
      }
      if (h == 0) af0 = af; else af1 = af;
    }
    #pragma unroll
    for (int q = 0; q < 4; ++q) {
      const size_t xb = (size_t)(q*16 + row16) * NK;
      short8 b0 = *(const short8*)&XT[xb + k0 + grp*8];
      short8 b1 = *(const short8*)&XT[xb + k0 + 32 + grp*8];
      acc[q] = __builtin_amdgcn_mfma_f32_16x16x32_bf16(af0, b0, acc[q], 0, 0, 0);
      acc[q] = __builtin_amdgcn_mfma_f32_16x16x32_bf16(af1, b1, acc[q], 0, 0, 0);
    }
  }

  // denominator: reduce the 4 lanes sharing this output row
  sw += __shfl_xor(sw, 16, 64);
  sw += __shfl_xor(sw, 32, 64);
  if (grp == 0) atomicAdd(&sumG[u], sw);

  // C/D layout: col = l&15, row = grp*4 + reg
  #pragma unroll
  for (int q = 0; q < 4; ++q) {
    #pragma unroll
    for (int r = 0; r < 4; ++r) {
      int uo = blockIdx.x*64 + wave*16 + grp*4 + r;
      atomicAdd(&accG[(size_t)uo*NF + q*16 + row16], acc[q][r]);
    }
  }
}

// ---------------- K4: normalize + bias + elu, write both outputs
__global__ __launch_bounds__(256) void finalize_kernel(
    const float* __restrict__ accST, const float* __restrict__ sumST,
    const float* __restrict__ accTS, const float* __restrict__ sumTS,
    const float* __restrict__ bias_s, const float* __restrict__ bias_t,
    float* __restrict__ out)
{
  int idx = blockIdx.x*256 + threadIdx.x;
  const int n0 = N_T*NF;
  float v;
  if (idx < n0) {
    int u = idx >> 6, f = idx & 63;
    float s = sumST[u];
    float r = s > 0.f ? accST[idx]/s : 0.f;
    v = r + bias_s[f];
  } else {
    int i2 = idx - n0;
    int u = i2 >> 6, f = i2 & 63;
    float s = sumTS[u];
    float r = s > 0.f ? accTS[i2]/s : 0.f;
    v = r + bias_t[f];
  }
  out[idx] = v > 0.f ? v : expm1f(v);
}

extern "C" void kernel_launch(void* const* d_in, const int* in_sizes, int n_in,
                              void* d_out, int out_size, void* d_ws, size_t ws_size,
                              hipStream_t stream)
{
  const float* hs     = (const float*)d_in[0];
  const float* ht     = (const float*)d_in[1];
  const int*   A      = (const int*)  d_in[2];
  const float* Ws     = (const float*)d_in[3];
  const float* Wt     = (const float*)d_in[4];
  const float* a1     = (const float*)d_in[5];
  const float* bias_s = (const float*)d_in[6];
  const float* bias_t = (const float*)d_in[7];
  float* out = (float*)d_out;

  unsigned short* XsT = (unsigned short*)d_ws;         // 64*8192 bf16
  unsigned short* XtT = XsT + (size_t)NF*N_S;          // 64*4096 bf16
  float* Whst  = (float*)(XtT + (size_t)NF*N_T);       // 8192
  float* Whtt  = Whst + N_S;                           // 4096
  float* mx    = Whtt + N_T;                           // 16 (padded)
  float* accST = mx + 16;                              // 4096*64
  float* sumST = accST + (size_t)N_T*NF;               // 4096
  float* accTS = sumST + N_T;                          // 8192*64
  float* sumTS = accTS + (size_t)N_S*NF;               // 8192

  hipMemsetAsync(accST, 0,
                 ((size_t)N_T*NF + N_T + (size_t)N_S*NF + N_S) * sizeof(float), stream);

  proj_kernel<<<(N_S + N_T)/4, 256, 0, stream>>>(hs, ht, Ws, Wt, a1, XsT, XtT, Whst, Whtt);
  max_kernel<<<2, 256, 0, stream>>>(Whst, Whtt, mx);
  agg_mfma<0><<<dim3(N_T/64, 16), 256, 0, stream>>>(A, Whtt, Whst, XsT, mx, accST, sumST, N_S/16);
  agg_mfma<1><<<dim3(N_S/64, 8),  256, 0, stream>>>(A, Whst, Whtt, XtT, mx, accTS, sumTS, N_T/8);
  finalize_kernel<<<(N_T*NF + N_S*NF)/256, 256, 0, stream>>>(accST, sumST, accTS, sumTS,
                                                             bias_s, bias_t, out);
}